// Round 1
// baseline (8705.564 us; speedup 1.0000x reference)
//
#include <hip/hip_runtime.h>

#define SEQ 512
#define DM 1024
#define NH 8
#define HD 128
#define FFN 4096
#define NL 4
#define NB 8

// ---------------- pos table: pos[j][c], j in [0,1024), pos_val = j-512 ----------------
__global__ void pos_kernel(float* __restrict__ pos) {
  int idx = blockIdx.x * blockDim.x + threadIdx.x;
  int j = idx >> 6, c = idx & 63;
  if (j >= 2 * SEQ) return;
  double inv = exp(-(double)c * (9.210340371976184 / 63.0));  // ln(10000)/63
  double p = (double)(j - SEQ) * inv;
  pos[j * HD + c] = (float)sin(p);
  pos[j * HD + 64 + c] = (float)cos(p);
}

// ---------------- generic fp32 GEMM: C = A@B (+bias)(+relu), row-major NN ----------------
// batched via grid.z with split strides (zb=z>>3, zh=z&7) for the PV use-case.
template<int BIAS, int RELU>
__global__ __launch_bounds__(256) void gemm_main(
    const float* __restrict__ A, int lda, long long sAz,
    const float* __restrict__ Bw, int ldb, long long sBb, long long sBh,
    const float* __restrict__ bias,
    float* __restrict__ C, int ldc, long long sCb, long long sCh,
    int M, int N, int K)
{
  __shared__ float As[8][132];
  __shared__ float Bs[8][132];
  const int z = blockIdx.z, zb = z >> 3, zh = z & 7;
  const float* Ab = A + (long long)z * sAz + (long long)blockIdx.y * 128 * lda;
  const float* Bb = Bw + (long long)zb * sBb + (long long)zh * sBh + blockIdx.x * 128;
  float* Cb = C + (long long)zb * sCb + (long long)zh * sCh
              + (long long)blockIdx.y * 128 * ldc + blockIdx.x * 128;
  const int tid = threadIdx.x;
  const int tr8 = (tid >> 4) * 8, tc8 = (tid & 15) * 8;
  const int ar = tid >> 3, ak = tid & 7;
  const int br = tid >> 7, bc = tid & 127;
  float acc[8][8] = {};
  for (int k0 = 0; k0 < K; k0 += 8) {
    __syncthreads();
#pragma unroll
    for (int i = 0; i < 4; i++)
      As[ak][ar + i * 32] = Ab[(long long)(ar + i * 32) * lda + (k0 + ak)];
#pragma unroll
    for (int i = 0; i < 4; i++)
      Bs[br + i * 2][bc] = Bb[(long long)(k0 + br + i * 2) * ldb + bc];
    __syncthreads();
#pragma unroll
    for (int k = 0; k < 8; k++) {
      const float4 a0 = *(const float4*)&As[k][tr8];
      const float4 a1 = *(const float4*)&As[k][tr8 + 4];
      const float4 b0 = *(const float4*)&Bs[k][tc8];
      const float4 b1 = *(const float4*)&Bs[k][tc8 + 4];
      const float av[8] = {a0.x,a0.y,a0.z,a0.w,a1.x,a1.y,a1.z,a1.w};
      const float bv[8] = {b0.x,b0.y,b0.z,b0.w,b1.x,b1.y,b1.z,b1.w};
#pragma unroll
      for (int ii = 0; ii < 8; ii++)
#pragma unroll
        for (int jj = 0; jj < 8; jj++)
          acc[ii][jj] = fmaf(av[ii], bv[jj], acc[ii][jj]);
    }
  }
  float bsv[8] = {};
  if (BIAS) {
#pragma unroll
    for (int j = 0; j < 8; j++) bsv[j] = bias[blockIdx.x * 128 + tc8 + j];
  }
#pragma unroll
  for (int i = 0; i < 8; i++) {
    float out[8];
#pragma unroll
    for (int j = 0; j < 8; j++) {
      float v = acc[i][j];
      if (BIAS) v += bsv[j];
      if (RELU) v = fmaxf(v, 0.f);
      out[j] = v;
    }
    float4* cp = (float4*)&Cb[(long long)(tr8 + i) * ldc + tc8];
    cp[0] = make_float4(out[0], out[1], out[2], out[3]);
    cp[1] = make_float4(out[4], out[5], out[6], out[7]);
  }
}

// ---------------- pass A: scores[z][q][j] = (Q_q + r_r_h) . K_j ----------------
__global__ __launch_bounds__(256) void attn_ac(
    const float* __restrict__ qkv, const float* __restrict__ rr,
    float* __restrict__ scores)
{
  __shared__ float As[64][36];
  __shared__ float Bs[64][36];
  const int z = blockIdx.z, b = z >> 3, h = z & 7;
  const int q0 = blockIdx.y * 64, j0 = blockIdx.x * 64;
  const float* Qb = qkv + (long long)b * SEQ * 3072 + h * HD;
  const float* Kb = Qb + DM;
  const float* rh = rr + h * HD;
  const int tid = threadIdx.x;
  const int sr = tid >> 5, sd = tid & 31;
  const int tr4 = (tid >> 4) * 4, tc = tid & 15;
  float acc[4][4] = {};
  for (int d0 = 0; d0 < HD; d0 += 32) {
    __syncthreads();
#pragma unroll
    for (int i = 0; i < 8; i++) {
      int r = sr + i * 8;
      As[r][sd] = Qb[(long long)(q0 + r) * 3072 + d0 + sd] + rh[d0 + sd];
      Bs[r][sd] = Kb[(long long)(j0 + r) * 3072 + d0 + sd];
    }
    __syncthreads();
#pragma unroll
    for (int dk = 0; dk < 32; dk += 4) {
      float4 a[4], bb[4];
#pragma unroll
      for (int ii = 0; ii < 4; ii++) a[ii] = *(const float4*)&As[tr4 + ii][dk];
#pragma unroll
      for (int jj = 0; jj < 4; jj++) bb[jj] = *(const float4*)&Bs[tc + 16 * jj][dk];
#pragma unroll
      for (int ii = 0; ii < 4; ii++)
#pragma unroll
        for (int jj = 0; jj < 4; jj++) {
          acc[ii][jj] = fmaf(a[ii].x, bb[jj].x, acc[ii][jj]);
          acc[ii][jj] = fmaf(a[ii].y, bb[jj].y, acc[ii][jj]);
          acc[ii][jj] = fmaf(a[ii].z, bb[jj].z, acc[ii][jj]);
          acc[ii][jj] = fmaf(a[ii].w, bb[jj].w, acc[ii][jj]);
        }
    }
  }
  float* Sb = scores + ((long long)z * SEQ + q0) * SEQ + j0;
#pragma unroll
  for (int ii = 0; ii < 4; ii++)
#pragma unroll
    for (int jj = 0; jj < 4; jj++)
      Sb[(long long)(tr4 + ii) * SEQ + tc + 16 * jj] = acc[ii][jj];
}

// ---------------- pass B: scores[z][q][m-512+q] += (Q_q + r_w_h) . pos[m] ----------------
__global__ __launch_bounds__(256) void attn_bshift(
    const float* __restrict__ qkv, const float* __restrict__ rw,
    const float* __restrict__ pos, float* __restrict__ scores)
{
  const int z = blockIdx.z, b = z >> 3, h = z & 7;
  const int q0 = blockIdx.y * 64, m0 = blockIdx.x * 64;
  const int lo = q0 + m0 - SEQ;
  if (lo > SEQ - 1 || lo < -126) return;
  __shared__ float As[64][36];
  __shared__ float Bs[64][36];
  const float* Qb = qkv + (long long)b * SEQ * 3072 + h * HD;
  const float* rh = rw + h * HD;
  const int tid = threadIdx.x;
  const int sr = tid >> 5, sd = tid & 31;
  const int tr4 = (tid >> 4) * 4, tc = tid & 15;
  float acc[4][4] = {};
  for (int d0 = 0; d0 < HD; d0 += 32) {
    __syncthreads();
#pragma unroll
    for (int i = 0; i < 8; i++) {
      int r = sr + i * 8;
      As[r][sd] = Qb[(long long)(q0 + r) * 3072 + d0 + sd] + rh[d0 + sd];
      Bs[r][sd] = pos[(long long)(m0 + r) * HD + d0 + sd];
    }
    __syncthreads();
#pragma unroll
    for (int dk = 0; dk < 32; dk += 4) {
      float4 a[4], bb[4];
#pragma unroll
      for (int ii = 0; ii < 4; ii++) a[ii] = *(const float4*)&As[tr4 + ii][dk];
#pragma unroll
      for (int jj = 0; jj < 4; jj++) bb[jj] = *(const float4*)&Bs[tc + 16 * jj][dk];
#pragma unroll
      for (int ii = 0; ii < 4; ii++)
#pragma unroll
        for (int jj = 0; jj < 4; jj++) {
          acc[ii][jj] = fmaf(a[ii].x, bb[jj].x, acc[ii][jj]);
          acc[ii][jj] = fmaf(a[ii].y, bb[jj].y, acc[ii][jj]);
          acc[ii][jj] = fmaf(a[ii].z, bb[jj].z, acc[ii][jj]);
          acc[ii][jj] = fmaf(a[ii].w, bb[jj].w, acc[ii][jj]);
        }
    }
  }
#pragma unroll
  for (int ii = 0; ii < 4; ii++) {
    int q = q0 + tr4 + ii;
#pragma unroll
    for (int jj = 0; jj < 4; jj++) {
      int j = (m0 + tc + 16 * jj) - SEQ + q;
      if (0 <= j && j < SEQ)
        scores[((long long)z * SEQ + q) * SEQ + j] += acc[ii][jj];
    }
  }
}

// ---------------- pass C: scores[m-512+j][j] += K_j . pos[m] (transposed shift) ----------------
__global__ __launch_bounds__(256) void attn_eshift(
    const float* __restrict__ qkv, const float* __restrict__ pos,
    float* __restrict__ scores)
{
  const int z = blockIdx.z, b = z >> 3, h = z & 7;
  const int j0 = blockIdx.y * 64, m0 = blockIdx.x * 64;
  const int qlo = j0 + m0 - SEQ;
  if (qlo > SEQ - 1 || qlo < -126) return;
  __shared__ float As[64][36];
  __shared__ float Bs[64][36];
  __shared__ float Ts[64][68];
  const float* Kb = qkv + (long long)b * SEQ * 3072 + DM + h * HD;
  const int tid = threadIdx.x;
  const int sr = tid >> 5, sd = tid & 31;
  const int tr4 = (tid >> 4) * 4, tc = tid & 15;
  float acc[4][4] = {};
  for (int d0 = 0; d0 < HD; d0 += 32) {
    __syncthreads();
#pragma unroll
    for (int i = 0; i < 8; i++) {
      int r = sr + i * 8;
      As[r][sd] = Kb[(long long)(j0 + r) * 3072 + d0 + sd];
      Bs[r][sd] = pos[(long long)(m0 + r) * HD + d0 + sd];
    }
    __syncthreads();
#pragma unroll
    for (int dk = 0; dk < 32; dk += 4) {
      float4 a[4], bb[4];
#pragma unroll
      for (int ii = 0; ii < 4; ii++) a[ii] = *(const float4*)&As[tr4 + ii][dk];
#pragma unroll
      for (int jj = 0; jj < 4; jj++) bb[jj] = *(const float4*)&Bs[tc + 16 * jj][dk];
#pragma unroll
      for (int ii = 0; ii < 4; ii++)
#pragma unroll
        for (int jj = 0; jj < 4; jj++) {
          acc[ii][jj] = fmaf(a[ii].x, bb[jj].x, acc[ii][jj]);
          acc[ii][jj] = fmaf(a[ii].y, bb[jj].y, acc[ii][jj]);
          acc[ii][jj] = fmaf(a[ii].z, bb[jj].z, acc[ii][jj]);
          acc[ii][jj] = fmaf(a[ii].w, bb[jj].w, acc[ii][jj]);
        }
    }
  }
  __syncthreads();
#pragma unroll
  for (int ii = 0; ii < 4; ii++)
#pragma unroll
    for (int jj = 0; jj < 4; jj++)
      Ts[tr4 + ii][tc + 16 * jj] = acc[ii][jj];
  __syncthreads();
  const int c = tid & 63;
  for (int r = tid >> 6; r < 127; r += 4) {
    int q = qlo + r;
    if ((unsigned)q < (unsigned)SEQ) {
      int j = j0 + c;
      int ml = q + SEQ - j - m0;
      if ((unsigned)ml < 64u)
        scores[((long long)z * SEQ + q) * SEQ + j] += Ts[c][ml];
    }
  }
}

// ---------------- softmax over key dim with mask ----------------
__global__ __launch_bounds__(256) void softmax_mask(
    float* __restrict__ scores, const int* __restrict__ mask)
{
  const int q = blockIdx.x, z = blockIdx.y, b = z >> 3;
  float* row = scores + ((long long)z * SEQ + q) * SEQ;
  const int tid = threadIdx.x;
  float v0 = row[tid], v1 = row[tid + 256];
  if (mask[b * SEQ + tid] == 0) v0 = -1e30f;
  if (mask[b * SEQ + tid + 256] == 0) v1 = -1e30f;
  __shared__ float red[4];
  float m = fmaxf(v0, v1);
  for (int o = 32; o; o >>= 1) m = fmaxf(m, __shfl_down(m, o));
  if ((tid & 63) == 0) red[tid >> 6] = m;
  __syncthreads();
  m = fmaxf(fmaxf(red[0], red[1]), fmaxf(red[2], red[3]));
  float e0 = __expf(v0 - m), e1 = __expf(v1 - m);
  float ssum = e0 + e1;
  for (int o = 32; o; o >>= 1) ssum += __shfl_down(ssum, o);
  __syncthreads();
  if ((tid & 63) == 0) red[tid >> 6] = ssum;
  __syncthreads();
  ssum = red[0] + red[1] + red[2] + red[3];
  float inv = 1.f / ssum;
  row[tid] = e0 * inv;
  row[tid + 256] = e1 * inv;
}

// ---------------- x = LayerNorm(x + a) * g + b, in-place on x ----------------
__global__ __launch_bounds__(256) void add_ln(
    float* __restrict__ x, const float* __restrict__ a,
    const float* __restrict__ g, const float* __restrict__ bt)
{
  const int row = blockIdx.x, tid = threadIdx.x;
  float4* xp = (float4*)(x + (size_t)row * DM);
  const float4* ap = (const float4*)(a + (size_t)row * DM);
  float4 xv = xp[tid], av = ap[tid];
  float4 s = make_float4(xv.x + av.x, xv.y + av.y, xv.z + av.z, xv.w + av.w);
  __shared__ float red[4];
  float sum = s.x + s.y + s.z + s.w;
  for (int o = 32; o; o >>= 1) sum += __shfl_down(sum, o);
  if ((tid & 63) == 0) red[tid >> 6] = sum;
  __syncthreads();
  float mu = (red[0] + red[1] + red[2] + red[3]) * (1.f / DM);
  float dx = s.x - mu, dy = s.y - mu, dz = s.z - mu, dw = s.w - mu;
  float sq = dx * dx + dy * dy + dz * dz + dw * dw;
  for (int o = 32; o; o >>= 1) sq += __shfl_down(sq, o);
  __syncthreads();
  if ((tid & 63) == 0) red[tid >> 6] = sq;
  __syncthreads();
  float var = (red[0] + red[1] + red[2] + red[3]) * (1.f / DM);
  float rstd = rsqrtf(var + 1e-5f);
  const float4 gv = ((const float4*)g)[tid];
  const float4 bv = ((const float4*)bt)[tid];
  xp[tid] = make_float4(dx * rstd * gv.x + bv.x, dy * rstd * gv.y + bv.y,
                        dz * rstd * gv.z + bv.z, dw * rstd * gv.w + bv.w);
}

extern "C" void kernel_launch(void* const* d_in, const int* in_sizes, int n_in,
                              void* d_out, int out_size, void* d_ws, size_t ws_size,
                              hipStream_t stream)
{
  const float* x_in = (const float*)d_in[0];
  const int*   mask = (const int*)d_in[1];
  const float* qkv_w = (const float*)d_in[2];
  const float* r_r  = (const float*)d_in[3];
  const float* r_w  = (const float*)d_in[4];
  const float* ln1g = (const float*)d_in[5];
  const float* ln1b = (const float*)d_in[6];
  const float* ln2g = (const float*)d_in[7];
  const float* ln2b = (const float*)d_in[8];
  const float* w1   = (const float*)d_in[9];
  const float* b1   = (const float*)d_in[10];
  const float* w2   = (const float*)d_in[11];
  const float* b2   = (const float*)d_in[12];
  float* x = (float*)d_out;
  char* ws = (char*)d_ws;

  const size_t pos_off = 0;
  const size_t qkv_off = 524288;                          // after pos (512KB)
  const size_t qkv_bytes = (size_t)NB * SEQ * 3072 * 4;   // 50331648
  const size_t scores_off = qkv_off + qkv_bytes;

  // attention batch-chunking so scores fits in ws
  int nb = 8;
  while (nb > 1) {
    size_t need = scores_off + (size_t)nb * 8 * SEQ * SEQ * 4 + (size_t)NB * SEQ * DM * 4;
    if (need <= ws_size) break;
    nb >>= 1;
  }
  const size_t scores_bytes = (size_t)nb * 8 * SEQ * SEQ * 4;
  const size_t a_off = scores_off + scores_bytes;

  float* pos    = (float*)(ws + pos_off);
  float* qkv    = (float*)(ws + qkv_off);
  float* scores = (float*)(ws + scores_off);
  float* aout   = (float*)(ws + a_off);

  // FFN row-chunking; h+f alias the (then-dead) qkv+scores region
  int R = 4096;
  while (R > 512 && (size_t)R * (FFN + DM) * 4 > qkv_bytes + scores_bytes) R >>= 1;
  float* hbuf = (float*)(ws + qkv_off);
  float* fbuf = (float*)(ws + qkv_off + (size_t)R * FFN * 4);

  hipMemcpyAsync(x, x_in, (size_t)out_size * 4, hipMemcpyDeviceToDevice, stream);
  pos_kernel<<<dim3(256), dim3(256), 0, stream>>>(pos);

  for (int L = 0; L < NL; L++) {
    const float* Wq = qkv_w + (size_t)L * DM * 3 * DM;
    gemm_main<0,0><<<dim3(3 * DM / 128, NB * SEQ / 128, 1), 256, 0, stream>>>(
        x, DM, 0, Wq, 3 * DM, 0, 0, nullptr,
        qkv, 3 * DM, 0, 0, NB * SEQ, 3 * DM, DM);

    for (int b0 = 0; b0 < NB; b0 += nb) {
      const float* qkv_b = qkv + (size_t)b0 * SEQ * 3072;
      attn_ac<<<dim3(8, 8, nb * 8), 256, 0, stream>>>(qkv_b, r_r + (size_t)L * NH * HD, scores);
      attn_bshift<<<dim3(16, 8, nb * 8), 256, 0, stream>>>(qkv_b, r_w + (size_t)L * NH * HD, pos, scores);
      attn_eshift<<<dim3(16, 8, nb * 8), 256, 0, stream>>>(qkv_b, pos, scores);
      softmax_mask<<<dim3(SEQ, nb * 8), 256, 0, stream>>>(scores, mask + (size_t)b0 * SEQ);
      gemm_main<0,0><<<dim3(1, SEQ / 128, nb * 8), 256, 0, stream>>>(
          scores, SEQ, (long long)SEQ * SEQ,
          qkv_b + 2 * DM, 3 * DM, (long long)SEQ * 3072, HD,
          nullptr,
          aout + (size_t)b0 * SEQ * DM, DM, (long long)SEQ * DM, HD,
          SEQ, HD, SEQ);
    }
    add_ln<<<dim3(NB * SEQ), 256, 0, stream>>>(x, aout, ln1g + (size_t)L * DM, ln1b + (size_t)L * DM);

    for (int r0 = 0; r0 < NB * SEQ; r0 += R) {
      gemm_main<1,1><<<dim3(FFN / 128, R / 128, 1), 256, 0, stream>>>(
          x + (size_t)r0 * DM, DM, 0, w1 + (size_t)L * DM * FFN, FFN, 0, 0,
          b1 + (size_t)L * FFN, hbuf, FFN, 0, 0, R, FFN, DM);
      gemm_main<1,0><<<dim3(DM / 128, R / 128, 1), 256, 0, stream>>>(
          hbuf, FFN, 0, w2 + (size_t)L * FFN * DM, DM, 0, 0,
          b2 + (size_t)L * DM, fbuf, DM, 0, 0, R, DM, FFN);
      add_ln<<<dim3(R), 256, 0, stream>>>(x + (size_t)r0 * DM, fbuf, ln2g + (size_t)L * DM, ln2b + (size_t)L * DM);
    }
  }
}

// Round 3
// 3154.268 us; speedup vs baseline: 2.7599x; 2.7599x over previous
//
#include <hip/hip_runtime.h>

#define SEQ 512
#define DM 1024
#define NH 8
#define HD 128
#define FFN 4096
#define NL 4
#define NB 8

typedef __attribute__((ext_vector_type(8))) _Float16 half8v;
typedef __attribute__((ext_vector_type(4))) float float4v;

__device__ __forceinline__ unsigned short f2h(float f) {
  _Float16 h = (_Float16)f;   // v_cvt_f16_f32, RNE
  return *(unsigned short*)&h;
}

// ---------------- pos table: pos[j][c], j in [0,1024), pos_val = j-512 ----------------
__global__ void pos_kernel(float* __restrict__ pos) {
  int idx = blockIdx.x * blockDim.x + threadIdx.x;
  int j = idx >> 6, c = idx & 63;
  if (j >= 2 * SEQ) return;
  double inv = exp(-(double)c * (9.210340371976184 / 63.0));  // ln(10000)/63
  double p = (double)(j - SEQ) * inv;
  pos[j * HD + c] = (float)sin(p);
  pos[j * HD + 64 + c] = (float)cos(p);
}

// ---------------- x copy + fp16 shadow ----------------
__global__ void cvt_copy(const float* __restrict__ in, float* __restrict__ xout,
                         unsigned short* __restrict__ xh, int n4) {
  int i = blockIdx.x * blockDim.x + threadIdx.x;
  if (i >= n4) return;
  float4 v = ((const float4*)in)[i];
  ((float4*)xout)[i] = v;
  ushort4 u;
  u.x = f2h(v.x); u.y = f2h(v.y); u.z = f2h(v.z); u.w = f2h(v.w);
  ((ushort4*)xh)[i] = u;
}

// ---------------- weight transpose + cvt: in fp32 [K][N] -> out fp16 [N][K] ----------------
__global__ __launch_bounds__(256) void transpose_cvt(
    const float* __restrict__ in, unsigned short* __restrict__ out, int K, int N) {
  __shared__ float t[32][33];
  int n0 = blockIdx.x * 32, k0 = blockIdx.y * 32;
  int c = threadIdx.x & 31, r = threadIdx.x >> 5;  // 8 rows per pass
#pragma unroll
  for (int i = 0; i < 32; i += 8)
    t[r + i][c] = in[(long long)(k0 + r + i) * N + n0 + c];
  __syncthreads();
#pragma unroll
  for (int i = 0; i < 32; i += 8)
    out[(long long)(n0 + r + i) * K + k0 + c] = f2h(t[c][r + i]);
}

// ---------------- fp16 MFMA GEMM: C[M][N] = A[M][K] @ Bt[N][K]^T ----------------
// 128x128 tile, BK=64, 4 waves (2x2), 16x16x32 f16 MFMA, st_16x32 swizzle,
// global_load_lds(16B) staging with pre-swizzled global source.
__device__ __forceinline__ void stage_tile(
    const unsigned short* __restrict__ g, int ld, int k0,
    unsigned short* lds, int wave, int lane) {
#pragma unroll
  for (int i = 0; i < 4; i++) {
    int p = wave * 256 + i * 64 + lane;
    int row = p >> 3, cs = p & 7;
    int c = cs ^ (row & 7);
    const unsigned short* src = g + (long long)row * ld + k0 + c * 8;
    __builtin_amdgcn_global_load_lds(
        (const __attribute__((address_space(1))) void*)src,
        (__attribute__((address_space(3))) void*)(lds + p * 8),
        16, 0, 0);
  }
}

template<int BIAS, int RELU, int OUTH>
__global__ __launch_bounds__(256) void gemm_mfma(
    const unsigned short* __restrict__ A, int lda,
    const unsigned short* __restrict__ Bt, int ldb,
    const float* __restrict__ bias,
    void* __restrict__ Cv, int ldc,
    int K) {
  __shared__ __align__(16) unsigned short Asm[128 * 64];
  __shared__ __align__(16) unsigned short Bsm[128 * 64];
  const int tid = threadIdx.x, lane = tid & 63, wave = tid >> 6;
  const int wr = wave >> 1, wc = wave & 1;
  // XCD-aware swizzle (caller guarantees nwg % 8 == 0)
  int nwg = gridDim.x * gridDim.y;
  int lin = blockIdx.y * gridDim.x + blockIdx.x;
  int swz = (lin & 7) * (nwg >> 3) + (lin >> 3);
  int bx = swz % gridDim.x, by = swz / gridDim.x;
  const unsigned short* Ag = A + (long long)by * 128 * lda;
  const unsigned short* Bg = Bt + (long long)bx * 128 * ldb;
  const int l15 = lane & 15, l4 = lane >> 4;
  float4v acc[4][4] = {};
  for (int k0 = 0; k0 < K; k0 += 64) {
    __syncthreads();
    stage_tile(Ag, lda, k0, Asm, wave, lane);
    stage_tile(Bg, ldb, k0, Bsm, wave, lane);
    __syncthreads();
#pragma unroll
    for (int kk = 0; kk < 2; kk++) {
      half8v af[4], bf[4];
#pragma unroll
      for (int m = 0; m < 4; m++) {
        int row = wr * 64 + m * 16 + l15;
        int cs = (kk * 4 + l4) ^ (row & 7);
        af[m] = *(const half8v*)&Asm[row * 64 + cs * 8];
      }
#pragma unroll
      for (int n = 0; n < 4; n++) {
        int row = wc * 64 + n * 16 + l15;
        int cs = (kk * 4 + l4) ^ (row & 7);
        bf[n] = *(const half8v*)&Bsm[row * 64 + cs * 8];
      }
#pragma unroll
      for (int m = 0; m < 4; m++)
#pragma unroll
        for (int n = 0; n < 4; n++)
          acc[m][n] = __builtin_amdgcn_mfma_f32_16x16x32_f16(af[m], bf[n], acc[m][n], 0, 0, 0);
    }
  }
#pragma unroll
  for (int n = 0; n < 4; n++) {
    int ccol = bx * 128 + wc * 64 + n * 16 + l15;
    float bv = BIAS ? bias[ccol] : 0.f;
#pragma unroll
    for (int m = 0; m < 4; m++) {
      int crow0 = by * 128 + wr * 64 + m * 16 + l4 * 4;
#pragma unroll
      for (int j = 0; j < 4; j++) {
        float v = acc[m][n][j] + bv;
        if (RELU) v = fmaxf(v, 0.f);
        long long off = (long long)(crow0 + j) * ldc + ccol;
        if (OUTH) ((unsigned short*)Cv)[off] = f2h(v);
        else      ((float*)Cv)[off] = v;
      }
    }
  }
}

// ---------------- fp32 GEMM (attention PV only now) ----------------
template<int BIAS, int RELU>
__global__ __launch_bounds__(256) void gemm_main(
    const float* __restrict__ A, int lda, long long sAz,
    const float* __restrict__ Bw, int ldb, long long sBb, long long sBh,
    const float* __restrict__ bias,
    float* __restrict__ C, int ldc, long long sCb, long long sCh,
    int M, int N, int K)
{
  __shared__ float As[8][132];
  __shared__ float Bs[8][132];
  const int z = blockIdx.z, zb = z >> 3, zh = z & 7;
  const float* Ab = A + (long long)z * sAz + (long long)blockIdx.y * 128 * lda;
  const float* Bb = Bw + (long long)zb * sBb + (long long)zh * sBh + blockIdx.x * 128;
  float* Cb = C + (long long)zb * sCb + (long long)zh * sCh
              + (long long)blockIdx.y * 128 * ldc + blockIdx.x * 128;
  const int tid = threadIdx.x;
  const int tr8 = (tid >> 4) * 8, tc8 = (tid & 15) * 8;
  const int ar = tid >> 3, ak = tid & 7;
  const int br = tid >> 7, bc = tid & 127;
  float acc[8][8] = {};
  for (int k0 = 0; k0 < K; k0 += 8) {
    __syncthreads();
#pragma unroll
    for (int i = 0; i < 4; i++)
      As[ak][ar + i * 32] = Ab[(long long)(ar + i * 32) * lda + (k0 + ak)];
#pragma unroll
    for (int i = 0; i < 4; i++)
      Bs[br + i * 2][bc] = Bb[(long long)(k0 + br + i * 2) * ldb + bc];
    __syncthreads();
#pragma unroll
    for (int k = 0; k < 8; k++) {
      const float4 a0 = *(const float4*)&As[k][tr8];
      const float4 a1 = *(const float4*)&As[k][tr8 + 4];
      const float4 b0 = *(const float4*)&Bs[k][tc8];
      const float4 b1 = *(const float4*)&Bs[k][tc8 + 4];
      const float av[8] = {a0.x,a0.y,a0.z,a0.w,a1.x,a1.y,a1.z,a1.w};
      const float bv[8] = {b0.x,b0.y,b0.z,b0.w,b1.x,b1.y,b1.z,b1.w};
#pragma unroll
      for (int ii = 0; ii < 8; ii++)
#pragma unroll
        for (int jj = 0; jj < 8; jj++)
          acc[ii][jj] = fmaf(av[ii], bv[jj], acc[ii][jj]);
    }
  }
#pragma unroll
  for (int i = 0; i < 8; i++) {
    float out[8];
#pragma unroll
    for (int j = 0; j < 8; j++) out[j] = acc[i][j];
    float4* cp = (float4*)&Cb[(long long)(tr8 + i) * ldc + tc8];
    cp[0] = make_float4(out[0], out[1], out[2], out[3]);
    cp[1] = make_float4(out[4], out[5], out[6], out[7]);
  }
}

// ---------------- pass A: scores[z][q][j] = (Q_q + r_r_h) . K_j ----------------
__global__ __launch_bounds__(256) void attn_ac(
    const float* __restrict__ qkv, const float* __restrict__ rr,
    float* __restrict__ scores)
{
  __shared__ float As[64][36];
  __shared__ float Bs[64][36];
  const int z = blockIdx.z, b = z >> 3, h = z & 7;
  const int q0 = blockIdx.y * 64, j0 = blockIdx.x * 64;
  const float* Qb = qkv + (long long)b * SEQ * 3072 + h * HD;
  const float* Kb = Qb + DM;
  const float* rh = rr + h * HD;
  const int tid = threadIdx.x;
  const int sr = tid >> 5, sd = tid & 31;
  const int tr4 = (tid >> 4) * 4, tc = tid & 15;
  float acc[4][4] = {};
  for (int d0 = 0; d0 < HD; d0 += 32) {
    __syncthreads();
#pragma unroll
    for (int i = 0; i < 8; i++) {
      int r = sr + i * 8;
      As[r][sd] = Qb[(long long)(q0 + r) * 3072 + d0 + sd] + rh[d0 + sd];
      Bs[r][sd] = Kb[(long long)(j0 + r) * 3072 + d0 + sd];
    }
    __syncthreads();
#pragma unroll
    for (int dk = 0; dk < 32; dk += 4) {
      float4 a[4], bb[4];
#pragma unroll
      for (int ii = 0; ii < 4; ii++) a[ii] = *(const float4*)&As[tr4 + ii][dk];
#pragma unroll
      for (int jj = 0; jj < 4; jj++) bb[jj] = *(const float4*)&Bs[tc + 16 * jj][dk];
#pragma unroll
      for (int ii = 0; ii < 4; ii++)
#pragma unroll
        for (int jj = 0; jj < 4; jj++) {
          acc[ii][jj] = fmaf(a[ii].x, bb[jj].x, acc[ii][jj]);
          acc[ii][jj] = fmaf(a[ii].y, bb[jj].y, acc[ii][jj]);
          acc[ii][jj] = fmaf(a[ii].z, bb[jj].z, acc[ii][jj]);
          acc[ii][jj] = fmaf(a[ii].w, bb[jj].w, acc[ii][jj]);
        }
    }
  }
  float* Sb = scores + ((long long)z * SEQ + q0) * SEQ + j0;
#pragma unroll
  for (int ii = 0; ii < 4; ii++)
#pragma unroll
    for (int jj = 0; jj < 4; jj++)
      Sb[(long long)(tr4 + ii) * SEQ + tc + 16 * jj] = acc[ii][jj];
}

// ---------------- pass B: scores[z][q][m-512+q] += (Q_q + r_w_h) . pos[m] ----------------
__global__ __launch_bounds__(256) void attn_bshift(
    const float* __restrict__ qkv, const float* __restrict__ rw,
    const float* __restrict__ pos, float* __restrict__ scores)
{
  const int z = blockIdx.z, b = z >> 3, h = z & 7;
  const int q0 = blockIdx.y * 64, m0 = blockIdx.x * 64;
  const int lo = q0 + m0 - SEQ;
  if (lo > SEQ - 1 || lo < -126) return;
  __shared__ float As[64][36];
  __shared__ float Bs[64][36];
  const float* Qb = qkv + (long long)b * SEQ * 3072 + h * HD;
  const float* rh = rw + h * HD;
  const int tid = threadIdx.x;
  const int sr = tid >> 5, sd = tid & 31;
  const int tr4 = (tid >> 4) * 4, tc = tid & 15;
  float acc[4][4] = {};
  for (int d0 = 0; d0 < HD; d0 += 32) {
    __syncthreads();
#pragma unroll
    for (int i = 0; i < 8; i++) {
      int r = sr + i * 8;
      As[r][sd] = Qb[(long long)(q0 + r) * 3072 + d0 + sd] + rh[d0 + sd];
      Bs[r][sd] = pos[(long long)(m0 + r) * HD + d0 + sd];
    }
    __syncthreads();
#pragma unroll
    for (int dk = 0; dk < 32; dk += 4) {
      float4 a[4], bb[4];
#pragma unroll
      for (int ii = 0; ii < 4; ii++) a[ii] = *(const float4*)&As[tr4 + ii][dk];
#pragma unroll
      for (int jj = 0; jj < 4; jj++) bb[jj] = *(const float4*)&Bs[tc + 16 * jj][dk];
#pragma unroll
      for (int ii = 0; ii < 4; ii++)
#pragma unroll
        for (int jj = 0; jj < 4; jj++) {
          acc[ii][jj] = fmaf(a[ii].x, bb[jj].x, acc[ii][jj]);
          acc[ii][jj] = fmaf(a[ii].y, bb[jj].y, acc[ii][jj]);
          acc[ii][jj] = fmaf(a[ii].z, bb[jj].z, acc[ii][jj]);
          acc[ii][jj] = fmaf(a[ii].w, bb[jj].w, acc[ii][jj]);
        }
    }
  }
#pragma unroll
  for (int ii = 0; ii < 4; ii++) {
    int q = q0 + tr4 + ii;
#pragma unroll
    for (int jj = 0; jj < 4; jj++) {
      int j = (m0 + tc + 16 * jj) - SEQ + q;
      if (0 <= j && j < SEQ)
        scores[((long long)z * SEQ + q) * SEQ + j] += acc[ii][jj];
    }
  }
}

// ---------------- pass C: scores[m-512+j][j] += K_j . pos[m] (transposed shift) ----------------
__global__ __launch_bounds__(256) void attn_eshift(
    const float* __restrict__ qkv, const float* __restrict__ pos,
    float* __restrict__ scores)
{
  const int z = blockIdx.z, b = z >> 3, h = z & 7;
  const int j0 = blockIdx.y * 64, m0 = blockIdx.x * 64;
  const int qlo = j0 + m0 - SEQ;
  if (qlo > SEQ - 1 || qlo < -126) return;
  __shared__ float As[64][36];
  __shared__ float Bs[64][36];
  __shared__ float Ts[64][68];
  const float* Kb = qkv + (long long)b * SEQ * 3072 + DM + h * HD;
  const int tid = threadIdx.x;
  const int sr = tid >> 5, sd = tid & 31;
  const int tr4 = (tid >> 4) * 4, tc = tid & 15;
  float acc[4][4] = {};
  for (int d0 = 0; d0 < HD; d0 += 32) {
    __syncthreads();
#pragma unroll
    for (int i = 0; i < 8; i++) {
      int r = sr + i * 8;
      As[r][sd] = Kb[(long long)(j0 + r) * 3072 + d0 + sd];
      Bs[r][sd] = pos[(long long)(m0 + r) * HD + d0 + sd];
    }
    __syncthreads();
#pragma unroll
    for (int dk = 0; dk < 32; dk += 4) {
      float4 a[4], bb[4];
#pragma unroll
      for (int ii = 0; ii < 4; ii++) a[ii] = *(const float4*)&As[tr4 + ii][dk];
#pragma unroll
      for (int jj = 0; jj < 4; jj++) bb[jj] = *(const float4*)&Bs[tc + 16 * jj][dk];
#pragma unroll
      for (int ii = 0; ii < 4; ii++)
#pragma unroll
        for (int jj = 0; jj < 4; jj++) {
          acc[ii][jj] = fmaf(a[ii].x, bb[jj].x, acc[ii][jj]);
          acc[ii][jj] = fmaf(a[ii].y, bb[jj].y, acc[ii][jj]);
          acc[ii][jj] = fmaf(a[ii].z, bb[jj].z, acc[ii][jj]);
          acc[ii][jj] = fmaf(a[ii].w, bb[jj].w, acc[ii][jj]);
        }
    }
  }
  __syncthreads();
#pragma unroll
  for (int ii = 0; ii < 4; ii++)
#pragma unroll
    for (int jj = 0; jj < 4; jj++)
      Ts[tr4 + ii][tc + 16 * jj] = acc[ii][jj];
  __syncthreads();
  const int c = tid & 63;
  for (int r = tid >> 6; r < 127; r += 4) {
    int q = qlo + r;
    if ((unsigned)q < (unsigned)SEQ) {
      int j = j0 + c;
      int ml = q + SEQ - j - m0;
      if ((unsigned)ml < 64u)
        scores[((long long)z * SEQ + q) * SEQ + j] += Ts[c][ml];
    }
  }
}

// ---------------- softmax over key dim with mask ----------------
__global__ __launch_bounds__(256) void softmax_mask(
    float* __restrict__ scores, const int* __restrict__ mask)
{
  const int q = blockIdx.x, z = blockIdx.y, b = z >> 3;
  float* row = scores + ((long long)z * SEQ + q) * SEQ;
  const int tid = threadIdx.x;
  float v0 = row[tid], v1 = row[tid + 256];
  if (mask[b * SEQ + tid] == 0) v0 = -1e30f;
  if (mask[b * SEQ + tid + 256] == 0) v1 = -1e30f;
  __shared__ float red[4];
  float m = fmaxf(v0, v1);
  for (int o = 32; o; o >>= 1) m = fmaxf(m, __shfl_down(m, o));
  if ((tid & 63) == 0) red[tid >> 6] = m;
  __syncthreads();
  m = fmaxf(fmaxf(red[0], red[1]), fmaxf(red[2], red[3]));
  float e0 = __expf(v0 - m), e1 = __expf(v1 - m);
  float ssum = e0 + e1;
  for (int o = 32; o; o >>= 1) ssum += __shfl_down(ssum, o);
  __syncthreads();
  if ((tid & 63) == 0) red[tid >> 6] = ssum;
  __syncthreads();
  ssum = red[0] + red[1] + red[2] + red[3];
  float inv = 1.f / ssum;
  row[tid] = e0 * inv;
  row[tid + 256] = e1 * inv;
}

// ---------------- x = LayerNorm(x + a) * g + b, in-place, + fp16 shadow ----------------
__global__ __launch_bounds__(256) void add_ln_cvt(
    float* __restrict__ x, const float* __restrict__ a,
    const float* __restrict__ g, const float* __restrict__ bt,
    unsigned short* __restrict__ xh)
{
  const int row = blockIdx.x, tid = threadIdx.x;
  float4* xp = (float4*)(x + (size_t)row * DM);
  const float4* ap = (const float4*)(a + (size_t)row * DM);
  float4 xv = xp[tid], av = ap[tid];
  float4 s = make_float4(xv.x + av.x, xv.y + av.y, xv.z + av.z, xv.w + av.w);
  __shared__ float red[4];
  float sum = s.x + s.y + s.z + s.w;
  for (int o = 32; o; o >>= 1) sum += __shfl_down(sum, o);
  if ((tid & 63) == 0) red[tid >> 6] = sum;
  __syncthreads();
  float mu = (red[0] + red[1] + red[2] + red[3]) * (1.f / DM);
  float dx = s.x - mu, dy = s.y - mu, dz = s.z - mu, dw = s.w - mu;
  float sq = dx * dx + dy * dy + dz * dz + dw * dw;
  for (int o = 32; o; o >>= 1) sq += __shfl_down(sq, o);
  __syncthreads();
  if ((tid & 63) == 0) red[tid >> 6] = sq;
  __syncthreads();
  float var = (red[0] + red[1] + red[2] + red[3]) * (1.f / DM);
  float rstd = rsqrtf(var + 1e-5f);
  const float4 gv = ((const float4*)g)[tid];
  const float4 bv = ((const float4*)bt)[tid];
  float4 o4 = make_float4(dx * rstd * gv.x + bv.x, dy * rstd * gv.y + bv.y,
                          dz * rstd * gv.z + bv.z, dw * rstd * gv.w + bv.w);
  xp[tid] = o4;
  ushort4 u;
  u.x = f2h(o4.x); u.y = f2h(o4.y); u.z = f2h(o4.z); u.w = f2h(o4.w);
  ((ushort4*)(xh + (size_t)row * DM))[tid] = u;
}

extern "C" void kernel_launch(void* const* d_in, const int* in_sizes, int n_in,
                              void* d_out, int out_size, void* d_ws, size_t ws_size,
                              hipStream_t stream)
{
  const float* x_in = (const float*)d_in[0];
  const int*   mask = (const int*)d_in[1];
  const float* qkv_w = (const float*)d_in[2];
  const float* r_r  = (const float*)d_in[3];
  const float* r_w  = (const float*)d_in[4];
  const float* ln1g = (const float*)d_in[5];
  const float* ln1b = (const float*)d_in[6];
  const float* ln2g = (const float*)d_in[7];
  const float* ln2b = (const float*)d_in[8];
  const float* w1   = (const float*)d_in[9];
  const float* b1   = (const float*)d_in[10];
  const float* w2   = (const float*)d_in[11];
  const float* b2   = (const float*)d_in[12];
  float* x = (float*)d_out;
  char* ws = (char*)d_ws;

  const int ROWS = NB * SEQ;  // 4096

  // workspace layout (bytes)
  const size_t pos_off = 0;                              // 512 KB
  const size_t xh_off  = 0x80000;                        // 8 MB fp16 activations
  const size_t wt_off  = xh_off + (size_t)ROWS * DM * 2; // 8 MB fp16 weight^T
  const size_t f_off   = wt_off + (size_t)FFN * DM * 2;  // 16 MB fp32 (aout / ffn out)
  const size_t qkv_off = f_off + (size_t)ROWS * DM * 4;  // 48 MB fp32 qkv / 32 MB fp16 h
  const size_t scores_off = qkv_off + (size_t)ROWS * 3 * DM * 4;

  int nb = 8;
  while (nb > 1) {
    size_t need = scores_off + (size_t)nb * 8 * SEQ * SEQ * 4;
    if (need <= ws_size) break;
    nb >>= 1;
  }

  float* pos    = (float*)(ws + pos_off);
  unsigned short* xh = (unsigned short*)(ws + xh_off);
  unsigned short* wt = (unsigned short*)(ws + wt_off);
  float* aout   = (float*)(ws + f_off);
  float* fbuf   = (float*)(ws + f_off);
  float* qkv    = (float*)(ws + qkv_off);
  unsigned short* hb = (unsigned short*)(ws + qkv_off);
  float* scores = (float*)(ws + scores_off);

  pos_kernel<<<dim3(256), dim3(256), 0, stream>>>(pos);
  cvt_copy<<<dim3(ROWS * DM / 4 / 256), 256, 0, stream>>>(x_in, x, xh, ROWS * DM / 4);

  for (int L = 0; L < NL; L++) {
    // QKV: qkv = xh @ Wqkv   (Wqkv^T into wt)
    transpose_cvt<<<dim3(3 * DM / 32, DM / 32), 256, 0, stream>>>(
        qkv_w + (size_t)L * DM * 3 * DM, wt, DM, 3 * DM);
    gemm_mfma<0,0,0><<<dim3(3 * DM / 128, ROWS / 128), 256, 0, stream>>>(
        xh, DM, wt, DM, nullptr, qkv, 3 * DM, DM);

    for (int b0 = 0; b0 < NB; b0 += nb) {
      const float* qkv_b = qkv + (size_t)b0 * SEQ * 3072;
      attn_ac<<<dim3(8, 8, nb * 8), 256, 0, stream>>>(qkv_b, r_r + (size_t)L * NH * HD, scores);
      attn_bshift<<<dim3(16, 8, nb * 8), 256, 0, stream>>>(qkv_b, r_w + (size_t)L * NH * HD, pos, scores);
      attn_eshift<<<dim3(16, 8, nb * 8), 256, 0, stream>>>(qkv_b, pos, scores);
      softmax_mask<<<dim3(SEQ, nb * 8), 256, 0, stream>>>(scores, mask + (size_t)b0 * SEQ);
      gemm_main<0,0><<<dim3(1, SEQ / 128, nb * 8), 256, 0, stream>>>(
          scores, SEQ, (long long)SEQ * SEQ,
          qkv_b + 2 * DM, 3 * DM, (long long)SEQ * 3072, HD,
          nullptr,
          aout + (size_t)b0 * SEQ * DM, DM, (long long)SEQ * DM, HD,
          SEQ, HD, SEQ);
    }
    add_ln_cvt<<<dim3(ROWS), 256, 0, stream>>>(x, aout, ln1g + (size_t)L * DM, ln1b + (size_t)L * DM, xh);

    // FFN1: hb(fp16) = relu(xh @ w1 + b1)
    transpose_cvt<<<dim3(FFN / 32, DM / 32), 256, 0, stream>>>(
        w1 + (size_t)L * DM * FFN, wt, DM, FFN);
    gemm_mfma<1,1,1><<<dim3(FFN / 128, ROWS / 128), 256, 0, stream>>>(
        xh, DM, wt, DM, b1 + (size_t)L * FFN, hb, FFN, DM);

    // FFN2: fbuf(fp32) = hb @ w2 + b2
    transpose_cvt<<<dim3(DM / 32, FFN / 32), 256, 0, stream>>>(
        w2 + (size_t)L * FFN * DM, wt, FFN, DM);
    gemm_mfma<1,0,0><<<dim3(DM / 128, ROWS / 128), 256, 0, stream>>>(
        hb, FFN, wt, FFN, b2 + (size_t)L * DM, fbuf, DM, FFN);

    add_ln_cvt<<<dim3(ROWS), 256, 0, stream>>>(x, fbuf, ln2g + (size_t)L * DM, ln2b + (size_t)L * DM, xh);
  }
}

// Round 4
// 1204.831 us; speedup vs baseline: 7.2255x; 2.6180x over previous
//
#include <hip/hip_runtime.h>

#define SEQ 512
#define DM 1024
#define NH 8
#define HD 128
#define FFN 4096
#define NL 4
#define NB 8

typedef __attribute__((ext_vector_type(8))) _Float16 half8v;
typedef __attribute__((ext_vector_type(4))) float float4v;

__device__ __forceinline__ unsigned short f2h(float f) {
  _Float16 h = (_Float16)f;
  return *(unsigned short*)&h;
}
__device__ __forceinline__ float h2f(unsigned short u) {
  _Float16 h = *(_Float16*)&u;
  return (float)h;
}

// ---------------- sc table: sc[q][c]=sin(q*a_c), sc[q][64+c]=cos(q*a_c), q<512,c<64 ----------------
__global__ void sc_kernel(float* __restrict__ sc) {
  int idx = blockIdx.x * blockDim.x + threadIdx.x;
  int q = idx >> 6, c = idx & 63;
  if (q >= SEQ) return;
  double a = exp(-(double)c * (9.210340371976184 / 63.0));  // ln(10000)/63
  double p = (double)q * a;
  sc[q * 128 + c] = (float)sin(p);
  sc[q * 128 + 64 + c] = (float)cos(p);
}

// ---------------- x copy + fp16 shadow ----------------
__global__ void cvt_copy(const float* __restrict__ in, float* __restrict__ xout,
                         unsigned short* __restrict__ xh, int n4) {
  int i = blockIdx.x * blockDim.x + threadIdx.x;
  if (i >= n4) return;
  float4 v = ((const float4*)in)[i];
  ((float4*)xout)[i] = v;
  ushort4 u;
  u.x = f2h(v.x); u.y = f2h(v.y); u.z = f2h(v.z); u.w = f2h(v.w);
  ((ushort4*)xh)[i] = u;
}

// ---------------- weight transpose + cvt: fp32 [K][N] -> fp16 [N][K] ----------------
__global__ __launch_bounds__(256) void transpose_cvt(
    const float* __restrict__ in, unsigned short* __restrict__ out, int K, int N) {
  __shared__ float t[32][33];
  int n0 = blockIdx.x * 32, k0 = blockIdx.y * 32;
  int c = threadIdx.x & 31, r = threadIdx.x >> 5;
#pragma unroll
  for (int i = 0; i < 32; i += 8)
    t[r + i][c] = in[(long long)(k0 + r + i) * N + n0 + c];
  __syncthreads();
#pragma unroll
  for (int i = 0; i < 32; i += 8)
    out[(long long)(n0 + r + i) * K + k0 + c] = f2h(t[c][r + i]);
}

// ---------------- staging: 128-row x 64-col fp16 tile, st_16x32 swizzle, 16B DMA ----------------
__device__ __forceinline__ void stage_tile(
    const unsigned short* __restrict__ g, int ld, int k0,
    unsigned short* lds, int wave, int lane) {
#pragma unroll
  for (int i = 0; i < 4; i++) {
    int p = wave * 256 + i * 64 + lane;
    int row = p >> 3, cs = p & 7;
    int c = cs ^ (row & 7);
    const unsigned short* src = g + (long long)row * ld + k0 + c * 8;
    __builtin_amdgcn_global_load_lds(
        (const __attribute__((address_space(1))) void*)src,
        (__attribute__((address_space(3))) void*)(lds + p * 8),
        16, 0, 0);
  }
}

// ---------------- fp16 MFMA GEMM (2D, weights): C[M][N] = A[M][K] @ Bt[N][K]^T ----------------
template<int BIAS, int RELU, int OUTH>
__global__ __launch_bounds__(256) void gemm_mfma(
    const unsigned short* __restrict__ A, int lda,
    const unsigned short* __restrict__ Bt, int ldb,
    const float* __restrict__ bias,
    void* __restrict__ Cv, int ldc,
    int K) {
  __shared__ __align__(16) unsigned short Asm[128 * 64];
  __shared__ __align__(16) unsigned short Bsm[128 * 64];
  const int tid = threadIdx.x, lane = tid & 63, wave = tid >> 6;
  const int wr = wave >> 1, wc = wave & 1;
  int nwg = gridDim.x * gridDim.y;
  int lin = blockIdx.y * gridDim.x + blockIdx.x;
  int swz = (lin & 7) * (nwg >> 3) + (lin >> 3);
  int bx = swz % gridDim.x, by = swz / gridDim.x;
  const unsigned short* Ag = A + (long long)by * 128 * lda;
  const unsigned short* Bg = Bt + (long long)bx * 128 * ldb;
  const int l15 = lane & 15, l4 = lane >> 4;
  float4v acc[4][4] = {};
  for (int k0 = 0; k0 < K; k0 += 64) {
    __syncthreads();
    stage_tile(Ag, lda, k0, Asm, wave, lane);
    stage_tile(Bg, ldb, k0, Bsm, wave, lane);
    __syncthreads();
#pragma unroll
    for (int kk = 0; kk < 2; kk++) {
      half8v af[4], bf[4];
#pragma unroll
      for (int m = 0; m < 4; m++) {
        int row = wr * 64 + m * 16 + l15;
        int cs = (kk * 4 + l4) ^ (row & 7);
        af[m] = *(const half8v*)&Asm[row * 64 + cs * 8];
      }
#pragma unroll
      for (int n = 0; n < 4; n++) {
        int row = wc * 64 + n * 16 + l15;
        int cs = (kk * 4 + l4) ^ (row & 7);
        bf[n] = *(const half8v*)&Bsm[row * 64 + cs * 8];
      }
#pragma unroll
      for (int m = 0; m < 4; m++)
#pragma unroll
        for (int n = 0; n < 4; n++)
          acc[m][n] = __builtin_amdgcn_mfma_f32_16x16x32_f16(af[m], bf[n], acc[m][n], 0, 0, 0);
    }
  }
#pragma unroll
  for (int n = 0; n < 4; n++) {
    int ccol = bx * 128 + wc * 64 + n * 16 + l15;
    float bv = BIAS ? bias[ccol] : 0.f;
#pragma unroll
    for (int m = 0; m < 4; m++) {
      int crow0 = by * 128 + wr * 64 + m * 16 + l4 * 4;
#pragma unroll
      for (int j = 0; j < 4; j++) {
        float v = acc[m][n][j] + bv;
        if (RELU) v = fmaxf(v, 0.f);
        long long off = (long long)(crow0 + j) * ldc + ccol;
        if (OUTH) ((unsigned short*)Cv)[off] = f2h(v);
        else      ((float*)Cv)[off] = v;
      }
    }
  }
}

// ---------------- batched fp16 MFMA GEMM (attention scores / PV) ----------------
template<int OUTH, int ZSH>
__global__ __launch_bounds__(256) void gemm_mfma_b(
    const unsigned short* __restrict__ A, int lda, long long sAz,
    const unsigned short* __restrict__ Bt, int ldb, long long sBz,
    void* __restrict__ Cv, int ldc, long long sCb, long long sCh,
    int K) {
  __shared__ __align__(16) unsigned short Asm[128 * 64];
  __shared__ __align__(16) unsigned short Bsm[128 * 64];
  const int tid = threadIdx.x, lane = tid & 63, wave = tid >> 6;
  const int wr = wave >> 1, wc = wave & 1;
  const int z = blockIdx.z, zb = z >> ZSH, zh = z & ((1 << ZSH) - 1);
  const int bx = blockIdx.x, by = blockIdx.y;
  const unsigned short* Ag = A + (long long)z * sAz + (long long)by * 128 * lda;
  const unsigned short* Bg = Bt + (long long)z * sBz + (long long)bx * 128 * ldb;
  const int l15 = lane & 15, l4 = lane >> 4;
  float4v acc[4][4] = {};
  for (int k0 = 0; k0 < K; k0 += 64) {
    __syncthreads();
    stage_tile(Ag, lda, k0, Asm, wave, lane);
    stage_tile(Bg, ldb, k0, Bsm, wave, lane);
    __syncthreads();
#pragma unroll
    for (int kk = 0; kk < 2; kk++) {
      half8v af[4], bf[4];
#pragma unroll
      for (int m = 0; m < 4; m++) {
        int row = wr * 64 + m * 16 + l15;
        int cs = (kk * 4 + l4) ^ (row & 7);
        af[m] = *(const half8v*)&Asm[row * 64 + cs * 8];
      }
#pragma unroll
      for (int n = 0; n < 4; n++) {
        int row = wc * 64 + n * 16 + l15;
        int cs = (kk * 4 + l4) ^ (row & 7);
        bf[n] = *(const half8v*)&Bsm[row * 64 + cs * 8];
      }
#pragma unroll
      for (int m = 0; m < 4; m++)
#pragma unroll
        for (int n = 0; n < 4; n++)
          acc[m][n] = __builtin_amdgcn_mfma_f32_16x16x32_f16(af[m], bf[n], acc[m][n], 0, 0, 0);
    }
  }
  long long cbase = (long long)zb * sCb + (long long)zh * sCh;
#pragma unroll
  for (int n = 0; n < 4; n++) {
    int ccol = bx * 128 + wc * 64 + n * 16 + l15;
#pragma unroll
    for (int m = 0; m < 4; m++) {
      int crow0 = by * 128 + wr * 64 + m * 16 + l4 * 4;
#pragma unroll
      for (int j = 0; j < 4; j++) {
        float v = acc[m][n][j];
        long long off = cbase + (long long)(crow0 + j) * ldc + ccol;
        if (OUTH) ((unsigned short*)Cv)[off] = f2h(v);
        else      ((float*)Cv)[off] = v;
      }
    }
  }
}

// ---------------- build augmented A-hat/B-hat (fp16, K=384) ----------------
// Ahat[q] = [Q+r_r | S~q | C~q | S_q | C_q],  Bhat[j] = [K | S_j | C_j | K~s | K~c]
__global__ __launch_bounds__(256) void build_aug(
    const unsigned short* __restrict__ qkv_h,  // chunk base, rows [nb*512][3072]
    const float* __restrict__ rr, const float* __restrict__ rw,
    const float* __restrict__ sc,
    unsigned short* __restrict__ Ahat, unsigned short* __restrict__ Bhat)
{
  const int z = blockIdx.y, b = z >> 3, h = z & 7;
  const int r = threadIdx.x >> 7, lane = threadIdx.x & 127;
  const int q = blockIdx.x * 2 + r;
  __shared__ float Qf[2][128], Kf[2][128], SC[2][128];
  const unsigned short* row = qkv_h + ((long long)(b * SEQ + q)) * 3072 + h * HD;
  float qv = h2f(row[lane]);
  float kv = h2f(row[DM + lane]);
  Qf[r][lane] = qv + rw[h * HD + lane];
  Kf[r][lane] = kv;
  SC[r][lane] = sc[q * 128 + lane];
  __syncthreads();
  unsigned short* Arow = Ahat + ((long long)z * SEQ + q) * 384;
  unsigned short* Brow = Bhat + ((long long)z * SEQ + q) * 384;
  Arow[lane] = f2h(qv + rr[h * HD + lane]);
  Brow[lane] = f2h(kv);
  if (lane < 64) {
    float S = SC[r][lane], C = SC[r][64 + lane];
    Arow[128 + lane] = f2h(Qf[r][lane] * C + Qf[r][64 + lane] * S);
    Arow[256 + lane] = f2h(S);
    Brow[128 + lane] = f2h(S);
    Brow[256 + lane] = f2h(Kf[r][lane] * C + Kf[r][64 + lane] * S);
  } else {
    int c = lane - 64;
    float S = SC[r][c], C = SC[r][lane];
    Arow[192 + c] = f2h(Qf[r][lane] * C - Qf[r][c] * S);
    Arow[320 + c] = f2h(C);
    Brow[192 + c] = f2h(C);
    Brow[320 + c] = f2h(Kf[r][lane] * C - Kf[r][c] * S);
  }
}

// ---------------- V transpose per head: Vt[z][d][j] = V[b,j,h,d] (fp16) ----------------
__global__ __launch_bounds__(256) void transpose_v(
    const unsigned short* __restrict__ qkv_h, unsigned short* __restrict__ Vt)
{
  __shared__ unsigned short t[32][33];
  const int z = blockIdx.z, b = z >> 3, h = z & 7;
  const int d0 = blockIdx.x * 32, j0 = blockIdx.y * 32;
  const int c = threadIdx.x & 31, r = threadIdx.x >> 5;
#pragma unroll
  for (int i = 0; i < 32; i += 8)
    t[r + i][c] = qkv_h[((long long)(b * SEQ + j0 + r + i)) * 3072 + 2 * DM + h * HD + d0 + c];
  __syncthreads();
#pragma unroll
  for (int i = 0; i < 32; i += 8)
    Vt[(long long)z * HD * SEQ + (long long)(d0 + r + i) * SEQ + j0 + c] = t[c][r + i];
}

// ---------------- softmax over key dim with mask; writes fp16 probs in place ----------------
__global__ __launch_bounds__(256) void softmax_mask(
    float* __restrict__ scores, const int* __restrict__ mask)
{
  const int q = blockIdx.x, z = blockIdx.y, b = z >> 3;
  float* row = scores + ((long long)z * SEQ + q) * SEQ;
  const int tid = threadIdx.x;
  float v0 = row[tid], v1 = row[tid + 256];
  if (mask[b * SEQ + tid] == 0) v0 = -1e30f;
  if (mask[b * SEQ + tid + 256] == 0) v1 = -1e30f;
  __shared__ float red[4];
  float m = fmaxf(v0, v1);
  for (int o = 32; o; o >>= 1) m = fmaxf(m, __shfl_down(m, o));
  if ((tid & 63) == 0) red[tid >> 6] = m;
  __syncthreads();
  m = fmaxf(fmaxf(red[0], red[1]), fmaxf(red[2], red[3]));
  float e0 = __expf(v0 - m), e1 = __expf(v1 - m);
  float ssum = e0 + e1;
  for (int o = 32; o; o >>= 1) ssum += __shfl_down(ssum, o);
  __syncthreads();
  if ((tid & 63) == 0) red[tid >> 6] = ssum;
  __syncthreads();
  ssum = red[0] + red[1] + red[2] + red[3];
  float inv = 1.f / ssum;
  unsigned short* hrow = (unsigned short*)row;
  hrow[tid] = f2h(e0 * inv);
  hrow[tid + 256] = f2h(e1 * inv);
}

// ---------------- x = LayerNorm(x + a)*g + b, in-place, + fp16 shadow ----------------
__global__ __launch_bounds__(256) void add_ln_cvt(
    float* __restrict__ x, const float* __restrict__ a,
    const float* __restrict__ g, const float* __restrict__ bt,
    unsigned short* __restrict__ xh)
{
  const int row = blockIdx.x, tid = threadIdx.x;
  float4* xp = (float4*)(x + (size_t)row * DM);
  const float4* ap = (const float4*)(a + (size_t)row * DM);
  float4 xv = xp[tid], av = ap[tid];
  float4 s = make_float4(xv.x + av.x, xv.y + av.y, xv.z + av.z, xv.w + av.w);
  __shared__ float red[4];
  float sum = s.x + s.y + s.z + s.w;
  for (int o = 32; o; o >>= 1) sum += __shfl_down(sum, o);
  if ((tid & 63) == 0) red[tid >> 6] = sum;
  __syncthreads();
  float mu = (red[0] + red[1] + red[2] + red[3]) * (1.f / DM);
  float dx = s.x - mu, dy = s.y - mu, dz = s.z - mu, dw = s.w - mu;
  float sq = dx * dx + dy * dy + dz * dz + dw * dw;
  for (int o = 32; o; o >>= 1) sq += __shfl_down(sq, o);
  __syncthreads();
  if ((tid & 63) == 0) red[tid >> 6] = sq;
  __syncthreads();
  float var = (red[0] + red[1] + red[2] + red[3]) * (1.f / DM);
  float rstd = rsqrtf(var + 1e-5f);
  const float4 gv = ((const float4*)g)[tid];
  const float4 bv = ((const float4*)bt)[tid];
  float4 o4 = make_float4(dx * rstd * gv.x + bv.x, dy * rstd * gv.y + bv.y,
                          dz * rstd * gv.z + bv.z, dw * rstd * gv.w + bv.w);
  xp[tid] = o4;
  ushort4 u;
  u.x = f2h(o4.x); u.y = f2h(o4.y); u.z = f2h(o4.z); u.w = f2h(o4.w);
  ((ushort4*)(xh + (size_t)row * DM))[tid] = u;
}

extern "C" void kernel_launch(void* const* d_in, const int* in_sizes, int n_in,
                              void* d_out, int out_size, void* d_ws, size_t ws_size,
                              hipStream_t stream)
{
  const float* x_in = (const float*)d_in[0];
  const int*   mask = (const int*)d_in[1];
  const float* qkv_w = (const float*)d_in[2];
  const float* r_r  = (const float*)d_in[3];
  const float* r_w  = (const float*)d_in[4];
  const float* ln1g = (const float*)d_in[5];
  const float* ln1b = (const float*)d_in[6];
  const float* ln2g = (const float*)d_in[7];
  const float* ln2b = (const float*)d_in[8];
  const float* w1   = (const float*)d_in[9];
  const float* b1   = (const float*)d_in[10];
  const float* w2   = (const float*)d_in[11];
  const float* b2   = (const float*)d_in[12];
  float* x = (float*)d_out;
  char* ws = (char*)d_ws;

  const int ROWS = NB * SEQ;  // 4096

  // layout (bytes)
  const size_t sc_off   = 0;                                   // 256 KB
  const size_t xh_off   = 0x40000;                             // 8 MB
  const size_t wt_off   = xh_off + (size_t)ROWS * DM * 2;      // 8 MB
  const size_t f_off    = wt_off + (size_t)FFN * DM * 2;       // 16 MB
  const size_t qkvh_off = f_off + (size_t)ROWS * DM * 4;       // 24 MB fp16 qkv
  const size_t e_off    = qkvh_off + (size_t)ROWS * 3 * DM * 2;

  const size_t ffn_need = (size_t)ROWS * FFN * 2;              // 32 MB hb
  int nb = 8;
  while (nb > 1) {
    size_t ab = (size_t)nb * 8 * SEQ * 384 * 2;
    size_t vt = (size_t)nb * 8 * HD * SEQ * 2;
    size_t scb = (size_t)nb * 8 * SEQ * SEQ * 4;
    size_t att_need = 2 * ab + vt + scb;
    size_t need = e_off + (att_need > ffn_need ? att_need : ffn_need);
    if (need <= ws_size) break;
    nb >>= 1;
  }
  const size_t ab_bytes = (size_t)nb * 8 * SEQ * 384 * 2;
  const size_t vt_bytes = (size_t)nb * 8 * HD * SEQ * 2;

  float* sc     = (float*)(ws + sc_off);
  unsigned short* xh = (unsigned short*)(ws + xh_off);
  unsigned short* wt = (unsigned short*)(ws + wt_off);
  float* aout   = (float*)(ws + f_off);
  float* fbuf   = (float*)(ws + f_off);
  unsigned short* qkvh = (unsigned short*)(ws + qkvh_off);
  unsigned short* Ahat = (unsigned short*)(ws + e_off);
  unsigned short* Bhat = (unsigned short*)(ws + e_off + ab_bytes);
  unsigned short* Vt   = (unsigned short*)(ws + e_off + 2 * ab_bytes);
  float* scores = (float*)(ws + e_off + 2 * ab_bytes + vt_bytes);
  unsigned short* hb = (unsigned short*)(ws + e_off);

  sc_kernel<<<dim3(SEQ * 64 / 256), 256, 0, stream>>>(sc);
  cvt_copy<<<dim3(ROWS * DM / 4 / 256), 256, 0, stream>>>(x_in, x, xh, ROWS * DM / 4);

  for (int L = 0; L < NL; L++) {
    // QKV (fp16 out): qkvh = xh @ Wqkv^T
    transpose_cvt<<<dim3(3 * DM / 32, DM / 32), 256, 0, stream>>>(
        qkv_w + (size_t)L * DM * 3 * DM, wt, DM, 3 * DM);
    gemm_mfma<0,0,1><<<dim3(3 * DM / 128, ROWS / 128), 256, 0, stream>>>(
        xh, DM, wt, DM, nullptr, qkvh, 3 * DM, DM);

    for (int b0 = 0; b0 < NB; b0 += nb) {
      const unsigned short* qkvh_b = qkvh + (size_t)b0 * SEQ * 3072;
      build_aug<<<dim3(SEQ / 2, nb * 8), 256, 0, stream>>>(
          qkvh_b, r_r + (size_t)L * NH * HD, r_w + (size_t)L * NH * HD, sc, Ahat, Bhat);
      transpose_v<<<dim3(HD / 32, SEQ / 32, nb * 8), 256, 0, stream>>>(qkvh_b, Vt);
      // scores[z] = Ahat[z] @ Bhat[z]^T   (M=N=512, K=384)
      gemm_mfma_b<0,0><<<dim3(SEQ / 128, SEQ / 128, nb * 8), 256, 0, stream>>>(
          Ahat, 384, (long long)SEQ * 384,
          Bhat, 384, (long long)SEQ * 384,
          scores, SEQ, (long long)SEQ * SEQ, 0, 384);
      softmax_mask<<<dim3(SEQ, nb * 8), 256, 0, stream>>>(scores, mask + (size_t)b0 * SEQ);
      // aout[b,q,h*HD+d] = probs[z] @ Vt[z]^T  (M=512, N=128, K=512)
      gemm_mfma_b<0,3><<<dim3(1, SEQ / 128, nb * 8), 256, 0, stream>>>(
          (const unsigned short*)scores, 2 * SEQ, (long long)SEQ * 2 * SEQ,
          Vt, SEQ, (long long)HD * SEQ,
          aout + (size_t)b0 * SEQ * DM, DM, (long long)SEQ * DM, HD, SEQ);
    }
    add_ln_cvt<<<dim3(ROWS), 256, 0, stream>>>(x, aout, ln1g + (size_t)L * DM, ln1b + (size_t)L * DM, xh);

    // FFN1: hb(fp16) = relu(xh @ w1 + b1)
    transpose_cvt<<<dim3(FFN / 32, DM / 32), 256, 0, stream>>>(
        w1 + (size_t)L * DM * FFN, wt, DM, FFN);
    gemm_mfma<1,1,1><<<dim3(FFN / 128, ROWS / 128), 256, 0, stream>>>(
        xh, DM, wt, DM, b1 + (size_t)L * FFN, hb, FFN, DM);

    // FFN2: fbuf(fp32) = hb @ w2 + b2
    transpose_cvt<<<dim3(DM / 32, FFN / 32), 256, 0, stream>>>(
        w2 + (size_t)L * FFN * DM, wt, FFN, DM);
    gemm_mfma<1,0,0><<<dim3(DM / 128, ROWS / 128), 256, 0, stream>>>(
        hb, FFN, wt, FFN, b2 + (size_t)L * DM, fbuf, DM, FFN);

    add_ln_cvt<<<dim3(ROWS), 256, 0, stream>>>(x, fbuf, ln2g + (size_t)L * DM, ln2b + (size_t)L * DM, xh);
  }
}

// Round 5
// 1176.988 us; speedup vs baseline: 7.3965x; 1.0237x over previous
//
#include <hip/hip_runtime.h>

#define SEQ 512
#define DM 1024
#define NH 8
#define HD 128
#define FFN 4096
#define NL 4
#define NB 8

typedef __attribute__((ext_vector_type(8))) _Float16 half8v;
typedef __attribute__((ext_vector_type(4))) float float4v;

__device__ __forceinline__ unsigned short f2h(float f) {
  _Float16 h = (_Float16)f;
  return *(unsigned short*)&h;
}
__device__ __forceinline__ float h2f(unsigned short u) {
  _Float16 h = *(_Float16*)&u;
  return (float)h;
}

// ---------------- sc table: sc[q][c]=sin(q*a_c), sc[q][64+c]=cos(q*a_c), q<512,c<64 ----------------
__global__ void sc_kernel(float* __restrict__ sc) {
  int idx = blockIdx.x * blockDim.x + threadIdx.x;
  int q = idx >> 6, c = idx & 63;
  if (q >= SEQ) return;
  double a = exp(-(double)c * (9.210340371976184 / 63.0));  // ln(10000)/63
  double p = (double)q * a;
  sc[q * 128 + c] = (float)sin(p);
  sc[q * 128 + 64 + c] = (float)cos(p);
}

// ---------------- x copy + fp16 shadow ----------------
__global__ void cvt_copy(const float* __restrict__ in, float* __restrict__ xout,
                         unsigned short* __restrict__ xh, int n4) {
  int i = blockIdx.x * blockDim.x + threadIdx.x;
  if (i >= n4) return;
  float4 v = ((const float4*)in)[i];
  ((float4*)xout)[i] = v;
  ushort4 u;
  u.x = f2h(v.x); u.y = f2h(v.y); u.z = f2h(v.z); u.w = f2h(v.w);
  ((ushort4*)xh)[i] = u;
}

// ---------------- weight transpose + cvt: fp32 [K][N] -> fp16 [N][K] ----------------
__global__ __launch_bounds__(256) void transpose_cvt(
    const float* __restrict__ in, unsigned short* __restrict__ out, int K, int N) {
  __shared__ float t[32][33];
  int n0 = blockIdx.x * 32, k0 = blockIdx.y * 32;
  int c = threadIdx.x & 31, r = threadIdx.x >> 5;
#pragma unroll
  for (int i = 0; i < 32; i += 8)
    t[r + i][c] = in[(long long)(k0 + r + i) * N + n0 + c];
  __syncthreads();
#pragma unroll
  for (int i = 0; i < 32; i += 8)
    out[(long long)(n0 + r + i) * K + k0 + c] = f2h(t[c][r + i]);
}

// ---------------- staging: R-row x 64-col fp16 tile, st_16x32 swizzle, 16B DMA ----------------
template<int R>
__device__ __forceinline__ void stage_tile(
    const unsigned short* __restrict__ g, long long ld, int k0,
    unsigned short* lds, int tid) {
#pragma unroll
  for (int i = 0; i < R / 32; i++) {
    int p = i * 256 + tid;
    int row = p >> 3, cs = p & 7;
    int c = cs ^ (row & 7);
    const unsigned short* src = g + (long long)row * ld + k0 + c * 8;
    __builtin_amdgcn_global_load_lds(
        (const __attribute__((address_space(1))) void*)src,
        (__attribute__((address_space(3))) void*)(lds + p * 8),
        16, 0, 0);
  }
}

// ---------------- fp16 MFMA GEMM (2D, weights): C[M][N] = A[M][K] @ Bt[N][K]^T ----------------
// BM=128, BN=32*NF, 4 waves (2x2), per-wave 64 x 16*NF.
template<int BIAS, int RELU, int OUTH, int NF>
__global__ __launch_bounds__(256) void gemm_mfma(
    const unsigned short* __restrict__ A, int lda,
    const unsigned short* __restrict__ Bt, int ldb,
    const float* __restrict__ bias,
    void* __restrict__ Cv, int ldc,
    int K) {
  const int BN = 32 * NF;
  __shared__ __align__(16) unsigned short Asm[128 * 64];
  __shared__ __align__(16) unsigned short Bsm[BN * 64];
  const int tid = threadIdx.x, lane = tid & 63, wave = tid >> 6;
  const int wr = wave >> 1, wc = wave & 1;
  int nwg = gridDim.x * gridDim.y;
  int lin = blockIdx.y * gridDim.x + blockIdx.x;
  int swz = (lin & 7) * (nwg >> 3) + (lin >> 3);
  int bx = swz % gridDim.x, by = swz / gridDim.x;
  const unsigned short* Ag = A + (long long)by * 128 * lda;
  const unsigned short* Bg = Bt + (long long)bx * BN * ldb;
  const int l15 = lane & 15, l4 = lane >> 4;
  float4v acc[4][NF] = {};
  for (int k0 = 0; k0 < K; k0 += 64) {
    __syncthreads();
    stage_tile<128>(Ag, lda, k0, Asm, tid);
    stage_tile<BN>(Bg, ldb, k0, Bsm, tid);
    __syncthreads();
#pragma unroll
    for (int kk = 0; kk < 2; kk++) {
      half8v af[4], bf[NF];
#pragma unroll
      for (int m = 0; m < 4; m++) {
        int row = wr * 64 + m * 16 + l15;
        int cs = (kk * 4 + l4) ^ (row & 7);
        af[m] = *(const half8v*)&Asm[row * 64 + cs * 8];
      }
#pragma unroll
      for (int n = 0; n < NF; n++) {
        int row = wc * 16 * NF + n * 16 + l15;
        int cs = (kk * 4 + l4) ^ (row & 7);
        bf[n] = *(const half8v*)&Bsm[row * 64 + cs * 8];
      }
#pragma unroll
      for (int m = 0; m < 4; m++)
#pragma unroll
        for (int n = 0; n < NF; n++)
          acc[m][n] = __builtin_amdgcn_mfma_f32_16x16x32_f16(af[m], bf[n], acc[m][n], 0, 0, 0);
    }
  }
#pragma unroll
  for (int n = 0; n < NF; n++) {
    int ccol = bx * BN + wc * 16 * NF + n * 16 + l15;
    float bv = BIAS ? bias[ccol] : 0.f;
#pragma unroll
    for (int m = 0; m < 4; m++) {
      int crow0 = by * 128 + wr * 64 + m * 16 + l4 * 4;
#pragma unroll
      for (int j = 0; j < 4; j++) {
        float v = acc[m][n][j] + bv;
        if (RELU) v = fmaxf(v, 0.f);
        long long off = (long long)(crow0 + j) * ldc + ccol;
        if (OUTH) ((unsigned short*)Cv)[off] = f2h(v);
        else      ((float*)Cv)[off] = v;
      }
    }
  }
}

// ---------------- batched fp16 MFMA GEMM (attention scores / PV) ----------------
template<int OUTH, int ZSH, int NF>
__global__ __launch_bounds__(256) void gemm_mfma_b(
    const unsigned short* __restrict__ A, int lda, long long sAz,
    const unsigned short* __restrict__ Bt, int ldb, long long sBz,
    void* __restrict__ Cv, int ldc, long long sCb, long long sCh,
    int K) {
  const int BN = 32 * NF;
  __shared__ __align__(16) unsigned short Asm[128 * 64];
  __shared__ __align__(16) unsigned short Bsm[BN * 64];
  const int tid = threadIdx.x, lane = tid & 63, wave = tid >> 6;
  const int wr = wave >> 1, wc = wave & 1;
  const int z = blockIdx.z, zb = z >> ZSH, zh = z & ((1 << ZSH) - 1);
  const int bx = blockIdx.x, by = blockIdx.y;
  const unsigned short* Ag = A + (long long)z * sAz + (long long)by * 128 * lda;
  const unsigned short* Bg = Bt + (long long)z * sBz + (long long)bx * BN * ldb;
  const int l15 = lane & 15, l4 = lane >> 4;
  float4v acc[4][NF] = {};
  for (int k0 = 0; k0 < K; k0 += 64) {
    __syncthreads();
    stage_tile<128>(Ag, lda, k0, Asm, tid);
    stage_tile<BN>(Bg, ldb, k0, Bsm, tid);
    __syncthreads();
#pragma unroll
    for (int kk = 0; kk < 2; kk++) {
      half8v af[4], bf[NF];
#pragma unroll
      for (int m = 0; m < 4; m++) {
        int row = wr * 64 + m * 16 + l15;
        int cs = (kk * 4 + l4) ^ (row & 7);
        af[m] = *(const half8v*)&Asm[row * 64 + cs * 8];
      }
#pragma unroll
      for (int n = 0; n < NF; n++) {
        int row = wc * 16 * NF + n * 16 + l15;
        int cs = (kk * 4 + l4) ^ (row & 7);
        bf[n] = *(const half8v*)&Bsm[row * 64 + cs * 8];
      }
#pragma unroll
      for (int m = 0; m < 4; m++)
#pragma unroll
        for (int n = 0; n < NF; n++)
          acc[m][n] = __builtin_amdgcn_mfma_f32_16x16x32_f16(af[m], bf[n], acc[m][n], 0, 0, 0);
    }
  }
  long long cbase = (long long)zb * sCb + (long long)zh * sCh;
#pragma unroll
  for (int n = 0; n < NF; n++) {
    int ccol = bx * BN + wc * 16 * NF + n * 16 + l15;
#pragma unroll
    for (int m = 0; m < 4; m++) {
      int crow0 = by * 128 + wr * 64 + m * 16 + l4 * 4;
#pragma unroll
      for (int j = 0; j < 4; j++) {
        float v = acc[m][n][j];
        long long off = cbase + (long long)(crow0 + j) * ldc + ccol;
        if (OUTH) ((unsigned short*)Cv)[off] = f2h(v);
        else      ((float*)Cv)[off] = v;
      }
    }
  }
}

// ---------------- build augmented A-hat/B-hat (fp16, K=384) ----------------
// Ahat[q] = [Q+r_r | S~q | C~q | S_q | C_q],  Bhat[j] = [K | S_j | C_j | K~s | K~c]
__global__ __launch_bounds__(256) void build_aug(
    const unsigned short* __restrict__ qkv_h,
    const float* __restrict__ rr, const float* __restrict__ rw,
    const float* __restrict__ sc,
    unsigned short* __restrict__ Ahat, unsigned short* __restrict__ Bhat)
{
  const int z = blockIdx.y, b = z >> 3, h = z & 7;
  const int r = threadIdx.x >> 7, lane = threadIdx.x & 127;
  const int q = blockIdx.x * 2 + r;
  __shared__ float Qf[2][128], Kf[2][128], SC[2][128];
  const unsigned short* row = qkv_h + ((long long)(b * SEQ + q)) * 3072 + h * HD;
  float qv = h2f(row[lane]);
  float kv = h2f(row[DM + lane]);
  Qf[r][lane] = qv + rw[h * HD + lane];
  Kf[r][lane] = kv;
  SC[r][lane] = sc[q * 128 + lane];
  __syncthreads();
  unsigned short* Arow = Ahat + ((long long)z * SEQ + q) * 384;
  unsigned short* Brow = Bhat + ((long long)z * SEQ + q) * 384;
  Arow[lane] = f2h(qv + rr[h * HD + lane]);
  Brow[lane] = f2h(kv);
  if (lane < 64) {
    float S = SC[r][lane], C = SC[r][64 + lane];
    Arow[128 + lane] = f2h(Qf[r][lane] * C + Qf[r][64 + lane] * S);
    Arow[256 + lane] = f2h(S);
    Brow[128 + lane] = f2h(S);
    Brow[256 + lane] = f2h(Kf[r][lane] * C + Kf[r][64 + lane] * S);
  } else {
    int c = lane - 64;
    float S = SC[r][c], C = SC[r][lane];
    Arow[192 + c] = f2h(Qf[r][lane] * C - Qf[r][c] * S);
    Arow[320 + c] = f2h(C);
    Brow[192 + c] = f2h(C);
    Brow[320 + c] = f2h(Kf[r][lane] * C - Kf[r][c] * S);
  }
}

// ---------------- V transpose per head: Vt[z][d][j] = V[b,j,h,d] (fp16) ----------------
__global__ __launch_bounds__(256) void transpose_v(
    const unsigned short* __restrict__ qkv_h, unsigned short* __restrict__ Vt)
{
  __shared__ unsigned short t[32][33];
  const int z = blockIdx.z, b = z >> 3, h = z & 7;
  const int d0 = blockIdx.x * 32, j0 = blockIdx.y * 32;
  const int c = threadIdx.x & 31, r = threadIdx.x >> 5;
#pragma unroll
  for (int i = 0; i < 32; i += 8)
    t[r + i][c] = qkv_h[((long long)(b * SEQ + j0 + r + i)) * 3072 + 2 * DM + h * HD + d0 + c];
  __syncthreads();
#pragma unroll
  for (int i = 0; i < 32; i += 8)
    Vt[(long long)z * HD * SEQ + (long long)(d0 + r + i) * SEQ + j0 + c] = t[c][r + i];
}

// ---------------- softmax over key dim with mask; writes fp16 probs in place ----------------
__global__ __launch_bounds__(256) void softmax_mask(
    float* __restrict__ scores, const int* __restrict__ mask)
{
  const int q = blockIdx.x, z = blockIdx.y, b = z >> 3;
  float* row = scores + ((long long)z * SEQ + q) * SEQ;
  const int tid = threadIdx.x;
  float v0 = row[tid], v1 = row[tid + 256];
  if (mask[b * SEQ + tid] == 0) v0 = -1e30f;
  if (mask[b * SEQ + tid + 256] == 0) v1 = -1e30f;
  __shared__ float red[4];
  float m = fmaxf(v0, v1);
  for (int o = 32; o; o >>= 1) m = fmaxf(m, __shfl_down(m, o));
  if ((tid & 63) == 0) red[tid >> 6] = m;
  __syncthreads();
  m = fmaxf(fmaxf(red[0], red[1]), fmaxf(red[2], red[3]));
  float e0 = __expf(v0 - m), e1 = __expf(v1 - m);
  float ssum = e0 + e1;
  for (int o = 32; o; o >>= 1) ssum += __shfl_down(ssum, o);
  __syncthreads();
  if ((tid & 63) == 0) red[tid >> 6] = ssum;
  __syncthreads();
  ssum = red[0] + red[1] + red[2] + red[3];
  float inv = 1.f / ssum;
  unsigned short* hrow = (unsigned short*)row;
  hrow[tid] = f2h(e0 * inv);
  hrow[tid + 256] = f2h(e1 * inv);
}

// ---------------- x = LayerNorm(x + a)*g + b, in-place, + fp16 shadow ----------------
__global__ __launch_bounds__(256) void add_ln_cvt(
    float* __restrict__ x, const float* __restrict__ a,
    const float* __restrict__ g, const float* __restrict__ bt,
    unsigned short* __restrict__ xh)
{
  const int row = blockIdx.x, tid = threadIdx.x;
  float4* xp = (float4*)(x + (size_t)row * DM);
  const float4* ap = (const float4*)(a + (size_t)row * DM);
  float4 xv = xp[tid], av = ap[tid];
  float4 s = make_float4(xv.x + av.x, xv.y + av.y, xv.z + av.z, xv.w + av.w);
  __shared__ float red[4];
  float sum = s.x + s.y + s.z + s.w;
  for (int o = 32; o; o >>= 1) sum += __shfl_down(sum, o);
  if ((tid & 63) == 0) red[tid >> 6] = sum;
  __syncthreads();
  float mu = (red[0] + red[1] + red[2] + red[3]) * (1.f / DM);
  float dx = s.x - mu, dy = s.y - mu, dz = s.z - mu, dw = s.w - mu;
  float sq = dx * dx + dy * dy + dz * dz + dw * dw;
  for (int o = 32; o; o >>= 1) sq += __shfl_down(sq, o);
  __syncthreads();
  if ((tid & 63) == 0) red[tid >> 6] = sq;
  __syncthreads();
  float var = (red[0] + red[1] + red[2] + red[3]) * (1.f / DM);
  float rstd = rsqrtf(var + 1e-5f);
  const float4 gv = ((const float4*)g)[tid];
  const float4 bv = ((const float4*)bt)[tid];
  float4 o4 = make_float4(dx * rstd * gv.x + bv.x, dy * rstd * gv.y + bv.y,
                          dz * rstd * gv.z + bv.z, dw * rstd * gv.w + bv.w);
  xp[tid] = o4;
  ushort4 u;
  u.x = f2h(o4.x); u.y = f2h(o4.y); u.z = f2h(o4.z); u.w = f2h(o4.w);
  ((ushort4*)(xh + (size_t)row * DM))[tid] = u;
}

extern "C" void kernel_launch(void* const* d_in, const int* in_sizes, int n_in,
                              void* d_out, int out_size, void* d_ws, size_t ws_size,
                              hipStream_t stream)
{
  const float* x_in = (const float*)d_in[0];
  const int*   mask = (const int*)d_in[1];
  const float* qkv_w = (const float*)d_in[2];
  const float* r_r  = (const float*)d_in[3];
  const float* r_w  = (const float*)d_in[4];
  const float* ln1g = (const float*)d_in[5];
  const float* ln1b = (const float*)d_in[6];
  const float* ln2g = (const float*)d_in[7];
  const float* ln2b = (const float*)d_in[8];
  const float* w1   = (const float*)d_in[9];
  const float* b1   = (const float*)d_in[10];
  const float* w2   = (const float*)d_in[11];
  const float* b2   = (const float*)d_in[12];
  float* x = (float*)d_out;
  char* ws = (char*)d_ws;

  const int ROWS = NB * SEQ;  // 4096

  // layout (bytes)
  const size_t sc_off   = 0;                                   // 256 KB
  const size_t xh_off   = 0x40000;                             // 8 MB
  const size_t wt_off   = xh_off + (size_t)ROWS * DM * 2;      // 8 MB
  const size_t f_off    = wt_off + (size_t)FFN * DM * 2;       // 16 MB
  const size_t qkvh_off = f_off + (size_t)ROWS * DM * 4;       // 24 MB fp16 qkv
  const size_t e_off    = qkvh_off + (size_t)ROWS * 3 * DM * 2;

  const size_t ffn_need = (size_t)ROWS * FFN * 2;              // 32 MB hb
  int nb = 8;
  while (nb > 1) {
    size_t ab = (size_t)nb * 8 * SEQ * 384 * 2;
    size_t vt = (size_t)nb * 8 * HD * SEQ * 2;
    size_t scb = (size_t)nb * 8 * SEQ * SEQ * 4;
    size_t att_need = 2 * ab + vt + scb;
    size_t need = e_off + (att_need > ffn_need ? att_need : ffn_need);
    if (need <= ws_size) break;
    nb >>= 1;
  }
  const size_t ab_bytes = (size_t)nb * 8 * SEQ * 384 * 2;
  const size_t vt_bytes = (size_t)nb * 8 * HD * SEQ * 2;

  float* sc     = (float*)(ws + sc_off);
  unsigned short* xh = (unsigned short*)(ws + xh_off);
  unsigned short* wt = (unsigned short*)(ws + wt_off);
  float* aout   = (float*)(ws + f_off);
  float* fbuf   = (float*)(ws + f_off);
  unsigned short* qkvh = (unsigned short*)(ws + qkvh_off);
  unsigned short* Ahat = (unsigned short*)(ws + e_off);
  unsigned short* Bhat = (unsigned short*)(ws + e_off + ab_bytes);
  unsigned short* Vt   = (unsigned short*)(ws + e_off + 2 * ab_bytes);
  float* scores = (float*)(ws + e_off + 2 * ab_bytes + vt_bytes);
  unsigned short* hb = (unsigned short*)(ws + e_off);

  sc_kernel<<<dim3(SEQ * 64 / 256), 256, 0, stream>>>(sc);
  cvt_copy<<<dim3(ROWS * DM / 4 / 256), 256, 0, stream>>>(x_in, x, xh, ROWS * DM / 4);

  for (int L = 0; L < NL; L++) {
    // QKV (fp16 out): qkvh = xh @ Wqkv^T
    transpose_cvt<<<dim3(3 * DM / 32, DM / 32), 256, 0, stream>>>(
        qkv_w + (size_t)L * DM * 3 * DM, wt, DM, 3 * DM);
    gemm_mfma<0,0,1,4><<<dim3(3 * DM / 128, ROWS / 128), 256, 0, stream>>>(
        xh, DM, wt, DM, nullptr, qkvh, 3 * DM, DM);

    for (int b0 = 0; b0 < NB; b0 += nb) {
      const unsigned short* qkvh_b = qkvh + (size_t)b0 * SEQ * 3072;
      build_aug<<<dim3(SEQ / 2, nb * 8), 256, 0, stream>>>(
          qkvh_b, r_r + (size_t)L * NH * HD, r_w + (size_t)L * NH * HD, sc, Ahat, Bhat);
      transpose_v<<<dim3(HD / 32, SEQ / 32, nb * 8), 256, 0, stream>>>(qkvh_b, Vt);
      // scores[z] = Ahat[z] @ Bhat[z]^T   (M=N=512, K=384), BN=64 -> 2048 blocks
      gemm_mfma_b<0,0,2><<<dim3(SEQ / 64, SEQ / 128, nb * 8), 256, 0, stream>>>(
          Ahat, 384, (long long)SEQ * 384,
          Bhat, 384, (long long)SEQ * 384,
          scores, SEQ, (long long)SEQ * SEQ, 0, 384);
      softmax_mask<<<dim3(SEQ, nb * 8), 256, 0, stream>>>(scores, mask + (size_t)b0 * SEQ);
      // aout = probs @ Vt^T  (M=512, N=128, K=512), BN=64 -> 512 blocks
      gemm_mfma_b<0,3,2><<<dim3(HD / 64, SEQ / 128, nb * 8), 256, 0, stream>>>(
          (const unsigned short*)scores, 2 * SEQ, (long long)SEQ * 2 * SEQ,
          Vt, SEQ, (long long)HD * SEQ,
          aout + (size_t)b0 * SEQ * DM, DM, (long long)SEQ * DM, HD, SEQ);
    }
    add_ln_cvt<<<dim3(ROWS), 256, 0, stream>>>(x, aout, ln1g + (size_t)L * DM, ln1b + (size_t)L * DM, xh);

    // FFN1: hb(fp16) = relu(xh @ w1 + b1), BN=128 (1024 blocks)
    transpose_cvt<<<dim3(FFN / 32, DM / 32), 256, 0, stream>>>(
        w1 + (size_t)L * DM * FFN, wt, DM, FFN);
    gemm_mfma<1,1,1,4><<<dim3(FFN / 128, ROWS / 128), 256, 0, stream>>>(
        xh, DM, wt, DM, b1 + (size_t)L * FFN, hb, FFN, DM);

    // FFN2: fbuf(fp32) = hb @ w2 + b2, BN=64 -> 512 blocks (2/CU)
    transpose_cvt<<<dim3(DM / 32, FFN / 32), 256, 0, stream>>>(
        w2 + (size_t)L * FFN * DM, wt, FFN, DM);
    gemm_mfma<1,0,0,2><<<dim3(DM / 64, ROWS / 128), 256, 0, stream>>>(
        hb, FFN, wt, FFN, b2 + (size_t)L * DM, fbuf, DM, FFN);

    add_ln_cvt<<<dim3(ROWS), 256, 0, stream>>>(x, fbuf, ln2g + (size_t)L * DM, ln2b + (size_t)L * DM, xh);
  }
}